// Round 1
// baseline (153.989 us; speedup 1.0000x reference)
//
#include <hip/hip_runtime.h>
#include <hip/hip_bf16.h>

// Problem constants
#define NE 384      // n_embed
#define HD 64       // head dim
#define TT 8        // block (sequence) length
#define NBATCH 32768

typedef __bf16 bf16;
typedef bf16 bf16x8 __attribute__((ext_vector_type(8)));
typedef bf16 bf16x4 __attribute__((ext_vector_type(4)));
typedef float f32x4 __attribute__((ext_vector_type(4)));

// ---------------------------------------------------------------------------
// Kernel 0: convert Wq|Wk|Wv (each [384,64] f32, row-major, y = x@W) into a
// bf16 fragment table in MFMA B-fragment order:
//   wt[((kk*12 + n)*64 + lane)*8 + j] = W_all[k][col]
//   with k = kk*32 + (lane>>4)*8 + j,  col = n*16 + (lane&15)
// so kernel 1 loads one fully-coalesced dwordx4 per lane per fragment.
// ---------------------------------------------------------------------------
__global__ void prep_wt(const float* __restrict__ Wq, const float* __restrict__ Wk,
                        const float* __restrict__ Wv, bf16* __restrict__ wt) {
    int c = blockIdx.x * blockDim.x + threadIdx.x;   // chunk id: one lane-slot (8 elems)
    if (c >= 12 * 12 * 64) return;
    int kk   = c / (12 * 64);
    int rem  = c % (12 * 64);
    int n    = rem / 64;
    int lane = rem % 64;
    int col  = n * 16 + (lane & 15);
    const float* src; int cc;
    if (col < 64)       { src = Wq; cc = col; }
    else if (col < 128) { src = Wk; cc = col - 64; }
    else                { src = Wv; cc = col - 128; }
    int k0 = kk * 32 + (lane >> 4) * 8;
    bf16* dst = wt + (size_t)c * 8;
    #pragma unroll
    for (int j = 0; j < 8; ++j)
        dst[j] = (bf16)src[(size_t)(k0 + j) * 64 + cc];
}

// ---------------------------------------------------------------------------
// Kernel 1: fused qkv projection + causal attention.
// Grid: 2048 blocks x 256 threads (4 waves). Each wave owns 4 batches
// (two 16-row M-tiles of the [262144 x 384] x-matrix).
// ---------------------------------------------------------------------------
template<bool PREP>
__global__ __launch_bounds__(256, 3)
void fused_head(const float* __restrict__ x, const bf16* __restrict__ wt,
                const float* __restrict__ Wq, const float* __restrict__ Wk,
                const float* __restrict__ Wv, float* __restrict__ out) {
    constexpr int STQ = 72;  // q2/k2 row stride (elems): 144 B (16B-aligned, 2-way banks)
    constexpr int STV = 40;  // vT/wei row stride (elems): 80 B (16B-aligned, 2-way banks)
    constexpr int WSZ = 2 * 16 * STQ + 64 * STV + 16 * STV;  // 5504 elems = 11008 B/wave
    __shared__ __align__(16) bf16 smem[4][WSZ];

    const int tid  = threadIdx.x;
    const int wid  = tid >> 6;
    const int lane = tid & 63;
    const int lr   = lane & 15;   // fragment row / col index
    const int lg   = lane >> 4;   // k-group

    bf16* q2  = smem[wid];                 // [16][STQ] row-major, cols 0..63 = q
    bf16* k2  = q2 + 16 * STQ;             // [16][STQ] row-major, cols 0..63 = k
    bf16* vT  = k2 + 16 * STQ;             // [64][STV]: vT[h][s] = v[s][h]; s 16..31 zero
    bf16* wei = vT + 64 * STV;             // [16][STV]: P block; cols 16..31 zero

    // One-time zero of the K=32 padding regions (cols 16..31); never rewritten.
    {
        unsigned int* z = (unsigned int*)(vT + lane * STV + 16);
        #pragma unroll
        for (int j = 0; j < 8; ++j) z[j] = 0u;
        if (lane < 16) {
            unsigned int* zw = (unsigned int*)(wei + lane * STV + 16);
            #pragma unroll
            for (int j = 0; j < 8; ++j) zw[j] = 0u;
        }
    }

    const int wg   = blockIdx.x * 4 + wid;   // global wave id
    const int row0 = wg * 32;                // first x-row of this wave (32 rows = 4 batches)

    f32x4 acc[2][12];
    #pragma unroll
    for (int m = 0; m < 2; ++m)
        #pragma unroll
        for (int n = 0; n < 12; ++n) acc[m][n] = f32x4{0.f, 0.f, 0.f, 0.f};

    // ---- projection GEMM: [32 x 384] @ [384 x 192] -------------------------
    const float* xb0 = x + (size_t)(row0 + lr) * NE + lg * 8;
    const float* xb1 = xb0 + (size_t)16 * NE;

    float4 c0lo = *(const float4*)(xb0);
    float4 c0hi = *(const float4*)(xb0 + 4);
    float4 c1lo = *(const float4*)(xb1);
    float4 c1hi = *(const float4*)(xb1 + 4);

    for (int kk = 0; kk < 12; ++kk) {
        bf16x8 a0, a1;
        a0[0] = (bf16)c0lo.x; a0[1] = (bf16)c0lo.y; a0[2] = (bf16)c0lo.z; a0[3] = (bf16)c0lo.w;
        a0[4] = (bf16)c0hi.x; a0[5] = (bf16)c0hi.y; a0[6] = (bf16)c0hi.z; a0[7] = (bf16)c0hi.w;
        a1[0] = (bf16)c1lo.x; a1[1] = (bf16)c1lo.y; a1[2] = (bf16)c1lo.z; a1[3] = (bf16)c1lo.w;
        a1[4] = (bf16)c1hi.x; a1[5] = (bf16)c1hi.y; a1[6] = (bf16)c1hi.z; a1[7] = (bf16)c1hi.w;

        if (kk < 11) {  // prefetch next K-step's A while this step's MFMAs run
            const float* p0 = xb0 + (kk + 1) * 32;
            const float* p1 = xb1 + (kk + 1) * 32;
            c0lo = *(const float4*)(p0);
            c0hi = *(const float4*)(p0 + 4);
            c1lo = *(const float4*)(p1);
            c1hi = *(const float4*)(p1 + 4);
        }

        if (PREP) {
            const bf16x8* bp = (const bf16x8*)wt + (size_t)(kk * 12) * 64 + lane;
            #pragma unroll
            for (int n = 0; n < 12; ++n) {
                bf16x8 b = bp[n * 64];
                acc[0][n] = __builtin_amdgcn_mfma_f32_16x16x32_bf16(a0, b, acc[0][n], 0, 0, 0);
                acc[1][n] = __builtin_amdgcn_mfma_f32_16x16x32_bf16(a1, b, acc[1][n], 0, 0, 0);
            }
        } else {  // fallback: gather weights fp32 (slow path, only if ws too small)
            #pragma unroll
            for (int n = 0; n < 12; ++n) {
                int col = n * 16 + lr;
                const float* ws = (col < 64) ? (Wq + col)
                                 : (col < 128) ? (Wk + (col - 64))
                                               : (Wv + (col - 128));
                bf16x8 b;
                #pragma unroll
                for (int j = 0; j < 8; ++j)
                    b[j] = (bf16)ws[(size_t)(kk * 32 + lg * 8 + j) * 64];
                acc[0][n] = __builtin_amdgcn_mfma_f32_16x16x32_bf16(a0, b, acc[0][n], 0, 0, 0);
                acc[1][n] = __builtin_amdgcn_mfma_f32_16x16x32_bf16(a1, b, acc[1][n], 0, 0, 0);
            }
        }
    }

    // ---- attention per batch-pair (16 rows = 2 batches) --------------------
    const float qk_scale = 0.051031036307982884f;  // 384^-0.5 (faithful to reference)
    const f32x4 zero4 = {0.f, 0.f, 0.f, 0.f};

    #pragma unroll     // MUST fully unroll: acc[p] with runtime p would spill to scratch
    for (int p = 0; p < 2; ++p) {
        // Stage qkv from C-layout accs (lane: col = lr, rows = 4*lg + r).
        #pragma unroll
        for (int nt = 0; nt < 4; ++nt) {
            #pragma unroll
            for (int r = 0; r < 4; ++r) {
                q2[(4 * lg + r) * STQ + nt * 16 + lr] = (bf16)acc[p][nt][r];
                k2[(4 * lg + r) * STQ + nt * 16 + lr] = (bf16)acc[p][4 + nt][r];
            }
            bf16x4 vv;
            vv[0] = (bf16)acc[p][8 + nt][0];
            vv[1] = (bf16)acc[p][8 + nt][1];
            vv[2] = (bf16)acc[p][8 + nt][2];
            vv[3] = (bf16)acc[p][8 + nt][3];
            *(bf16x4*)(vT + (nt * 16 + lr) * STV + lg * 4) = vv;  // transposed V
        }
        // (compiler inserts lgkmcnt waits for the read-after-write below)

        // QK^T on the stacked 16x16 two-batch block (K = 64 -> 2 MFMAs)
        f32x4 w4 = zero4;
        #pragma unroll
        for (int kh = 0; kh < 2; ++kh) {
            bf16x8 qa = *(const bf16x8*)(q2 + lr * STQ + kh * 32 + lg * 8);
            bf16x8 kb = *(const bf16x8*)(k2 + lr * STQ + kh * 32 + lg * 8);
            w4 = __builtin_amdgcn_mfma_f32_16x16x32_bf16(qa, kb, w4, 0, 0, 0);
        }

        // mask + softmax. lane holds col s' = lr, rows t' = 4*lg + r.
        const int sb = lr >> 3;    // key batch-half
        const int s  = lr & 7;     // key index within batch
        #pragma unroll
        for (int r = 0; r < 4; ++r) {
            int tp = 4 * lg + r;
            bool valid = ((tp >> 3) == sb) && (s <= (tp & 7));  // same batch & causal
            float val = valid ? w4[r] * qk_scale : -1e30f;
            float mx = val;
            mx = fmaxf(mx, __shfl_xor(mx, 1));
            mx = fmaxf(mx, __shfl_xor(mx, 2));
            mx = fmaxf(mx, __shfl_xor(mx, 4));
            float e = valid ? __expf(val - mx) : 0.f;
            float sm = e;
            sm += __shfl_xor(sm, 1);
            sm += __shfl_xor(sm, 2);
            sm += __shfl_xor(sm, 4);
            float pn = valid ? e / sm : 0.f;   // cross-batch quadrants -> exact 0
            wei[tp * STV + lr] = (bf16)pn;
        }

        // P @ V with K=32 (upper 16 k-slots are the pre-zeroed padding)
        bf16x8 pa = *(const bf16x8*)(wei + lr * STV + lg * 8);
        const int bb = wg * 4 + p * 2;
        #pragma unroll
        for (int nt = 0; nt < 4; ++nt) {
            bf16x8 vb = *(const bf16x8*)(vT + (nt * 16 + lr) * STV + lg * 8);
            f32x4 o = __builtin_amdgcn_mfma_f32_16x16x32_bf16(pa, vb, zero4, 0, 0, 0);
            #pragma unroll
            for (int r = 0; r < 4; ++r) {
                int tp = 4 * lg + r;
                out[((size_t)(bb + (tp >> 3)) * TT + (tp & 7)) * HD + nt * 16 + lr] = o[r];
            }
        }
    }
}

// ---------------------------------------------------------------------------
extern "C" void kernel_launch(void* const* d_in, const int* in_sizes, int n_in,
                              void* d_out, int out_size, void* d_ws, size_t ws_size,
                              hipStream_t stream) {
    const float* x  = (const float*)d_in[0];
    const float* Wq = (const float*)d_in[1];
    const float* Wk = (const float*)d_in[2];
    const float* Wv = (const float*)d_in[3];
    float* out = (float*)d_out;

    const size_t wt_bytes = (size_t)12 * 12 * 64 * 8 * sizeof(bf16);  // 147456
    const int grid = NBATCH / 16;   // 2048 blocks, 4 waves x 4 batches each

    if (ws_size >= wt_bytes) {
        bf16* wt = (bf16*)d_ws;
        prep_wt<<<36, 256, 0, stream>>>(Wq, Wk, Wv, wt);
        fused_head<true><<<grid, 256, 0, stream>>>(x, wt, nullptr, nullptr, nullptr, out);
    } else {
        fused_head<false><<<grid, 256, 0, stream>>>(x, nullptr, Wq, Wk, Wv, out);
    }
}

// Round 3
// 124.849 us; speedup vs baseline: 1.2334x; 1.2334x over previous
//
#include <hip/hip_runtime.h>
#include <hip/hip_bf16.h>

// Problem constants
#define NE 384      // n_embed
#define HD 64       // head dim
#define TT 8        // block (sequence) length
#define NBATCH 32768

typedef __bf16 bf16;
typedef bf16 bf16x8 __attribute__((ext_vector_type(8)));
typedef bf16 bf16x4 __attribute__((ext_vector_type(4)));
typedef float f32x4 __attribute__((ext_vector_type(4)));

// async global->LDS, 16B per lane, dest = wave-uniform LDS base + lane*16
#define GLOAD_LDS16(g, l) __builtin_amdgcn_global_load_lds(                    \
    (const __attribute__((address_space(1))) void*)(g),                        \
    (__attribute__((address_space(3))) void*)(l), 16, 0, 0)

// ---------------------------------------------------------------------------
// Kernel 0: convert Wq|Wk|Wv (each [384,64] f32, row-major, y = x@W) into a
// bf16 fragment table in MFMA B-fragment order:
//   wt[((kk*12 + n)*64 + lane)*8 + j] = W_all[k][col]
//   with k = kk*32 + (lane>>4)*8 + j,  col = n*16 + (lane&15)
// ---------------------------------------------------------------------------
__global__ void prep_wt(const float* __restrict__ Wq, const float* __restrict__ Wk,
                        const float* __restrict__ Wv, bf16* __restrict__ wt) {
    int c = blockIdx.x * blockDim.x + threadIdx.x;   // chunk id: one lane-slot (8 elems)
    if (c >= 12 * 12 * 64) return;
    int kk   = c / (12 * 64);
    int rem  = c % (12 * 64);
    int n    = rem / 64;
    int lane = rem % 64;
    int col  = n * 16 + (lane & 15);
    const float* src; int cc;
    if (col < 64)       { src = Wq; cc = col; }
    else if (col < 128) { src = Wk; cc = col - 64; }
    else                { src = Wv; cc = col - 128; }
    int k0 = kk * 32 + (lane >> 4) * 8;
    bf16* dst = wt + (size_t)c * 8;
    #pragma unroll
    for (int j = 0; j < 8; ++j)
        dst[j] = (bf16)src[(size_t)(k0 + j) * 64 + cc];
}

// ---------------------------------------------------------------------------
// Kernel 1: fused qkv projection + causal attention.
// Grid: 2048 blocks x 256 threads (4 waves). Each wave owns 4 batches
// (two 16-row M-tiles of the [262144 x 384] x-matrix).
// B fragments are staged per-BLOCK into LDS (double-buffered, async DMA) so
// all 4 waves share one copy: wt L2 traffic 1.2 GB -> 0.3 GB, and B-reads
// become pipelined ds_read_b128 instead of L2-latency-exposed global loads.
// The 24 KB B double-buffer is overlaid on the attention scratch (dead until
// after the final K-loop barrier).
// ---------------------------------------------------------------------------
template<bool PREP>
__global__ __launch_bounds__(256, 3)
void fused_head(const float* __restrict__ x, const bf16* __restrict__ wt,
                const float* __restrict__ Wq, const float* __restrict__ Wk,
                const float* __restrict__ Wv, float* __restrict__ out) {
    constexpr int STQ = 72;  // q2/k2 row stride (elems): 144 B (16B-aligned, 2-way banks)
    constexpr int STV = 40;  // vT/wei row stride (elems): 80 B (16B-aligned, 2-way banks)
    constexpr int WSZ = 2 * 16 * STQ + 64 * STV + 16 * STV;  // 5504 elems = 11008 B/wave
    constexpr int BBUF = 12 * 512;                           // 6144 elems = 12 KB / K-step
    __shared__ __align__(16) bf16 smem[4 * WSZ];             // 44032 B; >= 2*BBUF elems

    const int tid  = threadIdx.x;
    const int wid  = tid >> 6;
    const int lane = tid & 63;
    const int lr   = lane & 15;   // fragment row / col index
    const int lg   = lane >> 4;   // k-group

    // attention scratch (per-wave slice of the whole array; valid after K-loop)
    bf16* q2  = smem + wid * WSZ;          // [16][STQ] row-major, cols 0..63 = q
    bf16* k2  = q2 + 16 * STQ;             // [16][STQ] row-major, cols 0..63 = k
    bf16* vT  = k2 + 16 * STQ;             // [64][STV]: vT[h][s] = v[s][h]; s 16..31 zero
    bf16* wei = vT + 64 * STV;             // [16][STV]: P block; cols 16..31 zero

    const int wg   = blockIdx.x * 4 + wid;   // global wave id
    const int row0 = wg * 32;                // first x-row of this wave (32 rows = 4 batches)

    f32x4 acc[2][12];
    #pragma unroll
    for (int m = 0; m < 2; ++m)
        #pragma unroll
        for (int n = 0; n < 12; ++n) acc[m][n] = f32x4{0.f, 0.f, 0.f, 0.f};

    // ---- projection GEMM: [32 x 384] @ [384 x 192] -------------------------
    const float* xb0 = x + (size_t)(row0 + lr) * NE + lg * 8;
    const float* xb1 = xb0 + (size_t)16 * NE;

    f32x4 c0lo = __builtin_nontemporal_load((const f32x4*)(xb0));
    f32x4 c0hi = __builtin_nontemporal_load((const f32x4*)(xb0 + 4));
    f32x4 c1lo = __builtin_nontemporal_load((const f32x4*)(xb1));
    f32x4 c1hi = __builtin_nontemporal_load((const f32x4*)(xb1 + 4));

    if (PREP) {
        // prologue: stage K-step 0 into buffer 0 (3 fragments per wave)
        #pragma unroll
        for (int i = 0; i < 3; ++i) {
            int n = wid * 3 + i;
            GLOAD_LDS16(wt + ((size_t)(0 * 12 + n) * 64 + lane) * 8,
                        smem + n * 512);
        }
        __syncthreads();

        for (int kk = 0; kk < 12; ++kk) {
            const int cur = kk & 1;
            // issue async stage of next K-step's B fragments first (in flight
            // during this step's compute; completed by the end-of-step barrier)
            if (kk < 11) {
                #pragma unroll
                for (int i = 0; i < 3; ++i) {
                    int n = wid * 3 + i;
                    GLOAD_LDS16(wt + ((size_t)((kk + 1) * 12 + n) * 64 + lane) * 8,
                                smem + (cur ^ 1) * BBUF + n * 512);
                }
            }

            bf16x8 a0, a1;
            #pragma unroll
            for (int j = 0; j < 4; ++j) {
                a0[j]     = (bf16)c0lo[j];
                a0[j + 4] = (bf16)c0hi[j];
                a1[j]     = (bf16)c1lo[j];
                a1[j + 4] = (bf16)c1hi[j];
            }

            if (kk < 11) {  // prefetch next K-step's A while this step's MFMAs run
                const float* p0 = xb0 + (kk + 1) * 32;
                const float* p1 = xb1 + (kk + 1) * 32;
                c0lo = __builtin_nontemporal_load((const f32x4*)(p0));
                c0hi = __builtin_nontemporal_load((const f32x4*)(p0 + 4));
                c1lo = __builtin_nontemporal_load((const f32x4*)(p1));
                c1hi = __builtin_nontemporal_load((const f32x4*)(p1 + 4));
            }

            const bf16* bb = smem + cur * BBUF;
            #pragma unroll
            for (int n = 0; n < 12; ++n) {
                bf16x8 b = *(const bf16x8*)(bb + n * 512 + lane * 8);
                acc[0][n] = __builtin_amdgcn_mfma_f32_16x16x32_bf16(a0, b, acc[0][n], 0, 0, 0);
                acc[1][n] = __builtin_amdgcn_mfma_f32_16x16x32_bf16(a1, b, acc[1][n], 0, 0, 0);
            }
            __syncthreads();   // stage landed; buffers safe to swap
        }
    } else {  // fallback: gather weights fp32 (slow path, only if ws too small)
        for (int kk = 0; kk < 12; ++kk) {
            bf16x8 a0, a1;
            #pragma unroll
            for (int j = 0; j < 4; ++j) {
                a0[j]     = (bf16)c0lo[j];
                a0[j + 4] = (bf16)c0hi[j];
                a1[j]     = (bf16)c1lo[j];
                a1[j + 4] = (bf16)c1hi[j];
            }
            if (kk < 11) {
                const float* p0 = xb0 + (kk + 1) * 32;
                const float* p1 = xb1 + (kk + 1) * 32;
                c0lo = *(const f32x4*)(p0);
                c0hi = *(const f32x4*)(p0 + 4);
                c1lo = *(const f32x4*)(p1);
                c1hi = *(const f32x4*)(p1 + 4);
            }
            #pragma unroll
            for (int n = 0; n < 12; ++n) {
                int col = n * 16 + lr;
                const float* ws = (col < 64) ? (Wq + col)
                                 : (col < 128) ? (Wk + (col - 64))
                                               : (Wv + (col - 128));
                bf16x8 b;
                #pragma unroll
                for (int j = 0; j < 8; ++j)
                    b[j] = (bf16)ws[(size_t)(kk * 32 + lg * 8 + j) * 64];
                acc[0][n] = __builtin_amdgcn_mfma_f32_16x16x32_bf16(a0, b, acc[0][n], 0, 0, 0);
                acc[1][n] = __builtin_amdgcn_mfma_f32_16x16x32_bf16(a1, b, acc[1][n], 0, 0, 0);
            }
        }
    }

    // ---- zero the K=32 padding regions (cols 16..31) -----------------------
    // (must happen AFTER the K-loop: B staging overlays this LDS region)
    {
        unsigned int* z = (unsigned int*)(vT + lane * STV + 16);
        #pragma unroll
        for (int j = 0; j < 8; ++j) z[j] = 0u;
        if (lane < 16) {
            unsigned int* zw = (unsigned int*)(wei + lane * STV + 16);
            #pragma unroll
            for (int j = 0; j < 8; ++j) zw[j] = 0u;
        }
    }

    // ---- attention per batch-pair (16 rows = 2 batches) --------------------
    const float qk_scale = 0.051031036307982884f;  // 384^-0.5 (faithful to reference)
    const f32x4 zero4 = {0.f, 0.f, 0.f, 0.f};

    #pragma unroll     // MUST fully unroll: acc[p] with runtime p would spill to scratch
    for (int p = 0; p < 2; ++p) {
        // Stage qkv from C-layout accs (lane: col = lr, rows = 4*lg + r).
        #pragma unroll
        for (int nt = 0; nt < 4; ++nt) {
            #pragma unroll
            for (int r = 0; r < 4; ++r) {
                q2[(4 * lg + r) * STQ + nt * 16 + lr] = (bf16)acc[p][nt][r];
                k2[(4 * lg + r) * STQ + nt * 16 + lr] = (bf16)acc[p][4 + nt][r];
            }
            bf16x4 vv;
            vv[0] = (bf16)acc[p][8 + nt][0];
            vv[1] = (bf16)acc[p][8 + nt][1];
            vv[2] = (bf16)acc[p][8 + nt][2];
            vv[3] = (bf16)acc[p][8 + nt][3];
            *(bf16x4*)(vT + (nt * 16 + lr) * STV + lg * 4) = vv;  // transposed V
        }

        // QK^T on the stacked 16x16 two-batch block (K = 64 -> 2 MFMAs)
        f32x4 w4 = zero4;
        #pragma unroll
        for (int kh = 0; kh < 2; ++kh) {
            bf16x8 qa = *(const bf16x8*)(q2 + lr * STQ + kh * 32 + lg * 8);
            bf16x8 kb = *(const bf16x8*)(k2 + lr * STQ + kh * 32 + lg * 8);
            w4 = __builtin_amdgcn_mfma_f32_16x16x32_bf16(qa, kb, w4, 0, 0, 0);
        }

        // mask + softmax. lane holds col s' = lr, rows t' = 4*lg + r.
        const int sb = lr >> 3;    // key batch-half
        const int s  = lr & 7;     // key index within batch
        #pragma unroll
        for (int r = 0; r < 4; ++r) {
            int tp = 4 * lg + r;
            bool valid = ((tp >> 3) == sb) && (s <= (tp & 7));  // same batch & causal
            float val = valid ? w4[r] * qk_scale : -1e30f;
            float mx = val;
            mx = fmaxf(mx, __shfl_xor(mx, 1));
            mx = fmaxf(mx, __shfl_xor(mx, 2));
            mx = fmaxf(mx, __shfl_xor(mx, 4));
            float e = valid ? __expf(val - mx) : 0.f;
            float sm = e;
            sm += __shfl_xor(sm, 1);
            sm += __shfl_xor(sm, 2);
            sm += __shfl_xor(sm, 4);
            float pn = valid ? e / sm : 0.f;   // cross-batch quadrants -> exact 0
            wei[tp * STV + lr] = (bf16)pn;
        }

        // P @ V with K=32 (upper 16 k-slots are the pre-zeroed padding)
        bf16x8 pa = *(const bf16x8*)(wei + lr * STV + lg * 8);
        const int bb2 = wg * 4 + p * 2;
        #pragma unroll
        for (int nt = 0; nt < 4; ++nt) {
            bf16x8 vb = *(const bf16x8*)(vT + (nt * 16 + lr) * STV + lg * 8);
            f32x4 o = __builtin_amdgcn_mfma_f32_16x16x32_bf16(pa, vb, zero4, 0, 0, 0);
            #pragma unroll
            for (int r = 0; r < 4; ++r) {
                int tp = 4 * lg + r;
                __builtin_nontemporal_store(o[r],
                    &out[((size_t)(bb2 + (tp >> 3)) * TT + (tp & 7)) * HD + nt * 16 + lr]);
            }
        }
    }
}

// ---------------------------------------------------------------------------
extern "C" void kernel_launch(void* const* d_in, const int* in_sizes, int n_in,
                              void* d_out, int out_size, void* d_ws, size_t ws_size,
                              hipStream_t stream) {
    const float* x  = (const float*)d_in[0];
    const float* Wq = (const float*)d_in[1];
    const float* Wk = (const float*)d_in[2];
    const float* Wv = (const float*)d_in[3];
    float* out = (float*)d_out;

    const size_t wt_bytes = (size_t)12 * 12 * 64 * 8 * sizeof(bf16);  // 147456
    const int grid = NBATCH / 16;   // 2048 blocks, 4 waves x 4 batches each

    if (ws_size >= wt_bytes) {
        bf16* wt = (bf16*)d_ws;
        prep_wt<<<36, 256, 0, stream>>>(Wq, Wk, Wv, wt);
        fused_head<true><<<grid, 256, 0, stream>>>(x, wt, nullptr, nullptr, nullptr, out);
    } else {
        fused_head<false><<<grid, 256, 0, stream>>>(x, nullptr, Wq, Wk, Wv, out);
    }
}

// Round 4
// 122.580 us; speedup vs baseline: 1.2562x; 1.0185x over previous
//
#include <hip/hip_runtime.h>
#include <hip/hip_bf16.h>

// Problem constants
#define NE 384      // n_embed
#define HD 64       // head dim
#define TT 8        // block (sequence) length
#define NBATCH 32768

typedef __bf16 bf16;
typedef bf16 bf16x8 __attribute__((ext_vector_type(8)));
typedef bf16 bf16x4 __attribute__((ext_vector_type(4)));
typedef float f32x4 __attribute__((ext_vector_type(4)));

// async global->LDS, 16B per lane, dest = wave-uniform LDS base + lane*16
#define GLOAD_LDS16(g, l) __builtin_amdgcn_global_load_lds(                    \
    (const __attribute__((address_space(1))) void*)(g),                        \
    (__attribute__((address_space(3))) void*)(l), 16, 0, 0)

// ---------------------------------------------------------------------------
// Kernel 0: convert Wq|Wk|Wv (each [384,64] f32, row-major, y = x@W) into a
// bf16 fragment table in MFMA B-fragment order:
//   wt[((kk*12 + n)*64 + lane)*8 + j] = W_all[k][col]
//   with k = kk*32 + (lane>>4)*8 + j,  col = n*16 + (lane&15)
// ---------------------------------------------------------------------------
__global__ void prep_wt(const float* __restrict__ Wq, const float* __restrict__ Wk,
                        const float* __restrict__ Wv, bf16* __restrict__ wt) {
    int c = blockIdx.x * blockDim.x + threadIdx.x;   // chunk id: one lane-slot (8 elems)
    if (c >= 12 * 12 * 64) return;
    int kk   = c / (12 * 64);
    int rem  = c % (12 * 64);
    int n    = rem / 64;
    int lane = rem % 64;
    int col  = n * 16 + (lane & 15);
    const float* src; int cc;
    if (col < 64)       { src = Wq; cc = col; }
    else if (col < 128) { src = Wk; cc = col - 64; }
    else                { src = Wv; cc = col - 128; }
    int k0 = kk * 32 + (lane >> 4) * 8;
    bf16* dst = wt + (size_t)c * 8;
    #pragma unroll
    for (int j = 0; j < 8; ++j)
        dst[j] = (bf16)src[(size_t)(k0 + j) * 64 + cc];
}

// ---------------------------------------------------------------------------
// Kernel 1: fused qkv projection + causal attention — BARRIER-FREE K-loop.
// Grid: 1024 blocks x 512 threads (8 waves). Each wave owns 4 batches
// (two 16-row M-tiles). The ENTIRE fragment-ordered weight table (144 KB)
// is loaded into LDS once per block; the K-loop then has zero barriers and
// zero staging — each wave streams x with a 3-step register prefetch and
// reads B via conflict-free contiguous ds_read_b128. After one barrier the
// attention scratch (8 x 11 KB) overlays the dead weight region.
// ---------------------------------------------------------------------------
template<bool PREP>
__global__ __launch_bounds__(512, 2)
void fused_head(const float* __restrict__ x, const bf16* __restrict__ wt,
                const float* __restrict__ Wq, const float* __restrict__ Wk,
                const float* __restrict__ Wv, float* __restrict__ out) {
    constexpr int STQ = 72;  // q2/k2 row stride (elems): 144 B (16B-aligned, 2-way banks)
    constexpr int STV = 40;  // vT/wei row stride (elems): 80 B (16B-aligned, 2-way banks)
    constexpr int WSZ = 2 * 16 * STQ + 64 * STV + 16 * STV;  // 5504 elems/wave
    // 144 chunks x 512 elems = 73728 bf16 = 147456 B; >= 8 waves x WSZ (88064 B)
    __shared__ __align__(16) bf16 smem[73728];

    const int tid  = threadIdx.x;
    const int wid  = tid >> 6;    // 0..7
    const int lane = tid & 63;
    const int lr   = lane & 15;   // fragment row / col index
    const int lg   = lane >> 4;   // k-group

    const int wg   = blockIdx.x * 8 + wid;   // global wave id
    const int row0 = wg * 32;                // first x-row (32 rows = 4 batches)

    f32x4 acc[2][12];
    #pragma unroll
    for (int m = 0; m < 2; ++m)
        #pragma unroll
        for (int n = 0; n < 12; ++n) acc[m][n] = f32x4{0.f, 0.f, 0.f, 0.f};

    const float* xb0 = x + (size_t)(row0 + lr) * NE + lg * 8;
    const float* xb1 = xb0 + (size_t)16 * NE;

    // A prefetch ring: 3 K-steps in flight (fully unrolled -> static indexing)
    f32x4 ab[3][4];
    #pragma unroll
    for (int s = 0; s < 3; ++s) {
        const float* p0 = xb0 + s * 32;
        const float* p1 = xb1 + s * 32;
        ab[s][0] = __builtin_nontemporal_load((const f32x4*)(p0));
        ab[s][1] = __builtin_nontemporal_load((const f32x4*)(p0 + 4));
        ab[s][2] = __builtin_nontemporal_load((const f32x4*)(p1));
        ab[s][3] = __builtin_nontemporal_load((const f32x4*)(p1 + 4));
    }

    if (PREP) {
        // ---- load the whole weight table into LDS (one time, one barrier) --
        #pragma unroll
        for (int r = 0; r < 18; ++r) {
            int c = wid * 18 + r;                       // chunk id 0..143
            GLOAD_LDS16(wt + ((size_t)c * 64 + lane) * 8, smem + c * 512);
        }
        __syncthreads();

        // ---- projection K-loop: NO barriers, NO staging --------------------
        #pragma unroll
        for (int kk = 0; kk < 12; ++kk) {
            const int slot = kk % 3;
            bf16x8 a0, a1;
            #pragma unroll
            for (int j = 0; j < 4; ++j) {
                a0[j]     = (bf16)ab[slot][0][j];
                a0[j + 4] = (bf16)ab[slot][1][j];
                a1[j]     = (bf16)ab[slot][2][j];
                a1[j + 4] = (bf16)ab[slot][3][j];
            }
            if (kk + 3 < 12) {   // refill the slot just consumed (3 steps ahead)
                const float* p0 = xb0 + (kk + 3) * 32;
                const float* p1 = xb1 + (kk + 3) * 32;
                ab[slot][0] = __builtin_nontemporal_load((const f32x4*)(p0));
                ab[slot][1] = __builtin_nontemporal_load((const f32x4*)(p0 + 4));
                ab[slot][2] = __builtin_nontemporal_load((const f32x4*)(p1));
                ab[slot][3] = __builtin_nontemporal_load((const f32x4*)(p1 + 4));
            }
            #pragma unroll
            for (int n = 0; n < 12; ++n) {
                bf16x8 b = *(const bf16x8*)(smem + ((kk * 12 + n) * 64 + lane) * 8);
                acc[0][n] = __builtin_amdgcn_mfma_f32_16x16x32_bf16(a0, b, acc[0][n], 0, 0, 0);
                acc[1][n] = __builtin_amdgcn_mfma_f32_16x16x32_bf16(a1, b, acc[1][n], 0, 0, 0);
            }
        }
        __syncthreads();   // all waves done reading B -> overlay attn scratch
    } else {  // fallback: gather weights fp32 from global (slow, ws too small)
        #pragma unroll
        for (int kk = 0; kk < 12; ++kk) {
            const int slot = kk % 3;
            bf16x8 a0, a1;
            #pragma unroll
            for (int j = 0; j < 4; ++j) {
                a0[j]     = (bf16)ab[slot][0][j];
                a0[j + 4] = (bf16)ab[slot][1][j];
                a1[j]     = (bf16)ab[slot][2][j];
                a1[j + 4] = (bf16)ab[slot][3][j];
            }
            if (kk + 3 < 12) {
                const float* p0 = xb0 + (kk + 3) * 32;
                const float* p1 = xb1 + (kk + 3) * 32;
                ab[slot][0] = *(const f32x4*)(p0);
                ab[slot][1] = *(const f32x4*)(p0 + 4);
                ab[slot][2] = *(const f32x4*)(p1);
                ab[slot][3] = *(const f32x4*)(p1 + 4);
            }
            #pragma unroll
            for (int n = 0; n < 12; ++n) {
                int col = n * 16 + lr;
                const float* ws = (col < 64) ? (Wq + col)
                                 : (col < 128) ? (Wk + (col - 64))
                                               : (Wv + (col - 128));
                bf16x8 b;
                #pragma unroll
                for (int j = 0; j < 8; ++j)
                    b[j] = (bf16)ws[(size_t)(kk * 32 + lg * 8 + j) * 64];
                acc[0][n] = __builtin_amdgcn_mfma_f32_16x16x32_bf16(a0, b, acc[0][n], 0, 0, 0);
                acc[1][n] = __builtin_amdgcn_mfma_f32_16x16x32_bf16(a1, b, acc[1][n], 0, 0, 0);
            }
        }
        __syncthreads();
    }

    // ---- per-wave attention scratch (overlays the weight region) -----------
    bf16* q2  = smem + wid * WSZ;          // [16][STQ] row-major, cols 0..63 = q
    bf16* k2  = q2 + 16 * STQ;             // [16][STQ] row-major, cols 0..63 = k
    bf16* vT  = k2 + 16 * STQ;             // [64][STV]: vT[h][s] = v[s][h]; s 16..31 zero
    bf16* wei = vT + 64 * STV;             // [16][STV]: P block; cols 16..31 zero

    // zero the K=32 padding regions (cols 16..31)
    {
        unsigned int* z = (unsigned int*)(vT + lane * STV + 16);
        #pragma unroll
        for (int j = 0; j < 8; ++j) z[j] = 0u;
        if (lane < 16) {
            unsigned int* zw = (unsigned int*)(wei + lane * STV + 16);
            #pragma unroll
            for (int j = 0; j < 8; ++j) zw[j] = 0u;
        }
    }

    // ---- attention per batch-pair (16 rows = 2 batches) --------------------
    const float qk_scale = 0.051031036307982884f;  // 384^-0.5 (faithful to reference)
    const f32x4 zero4 = {0.f, 0.f, 0.f, 0.f};

    #pragma unroll     // MUST fully unroll: acc[p] with runtime p would spill to scratch
    for (int p = 0; p < 2; ++p) {
        // Stage qkv from C-layout accs (lane: col = lr, rows = 4*lg + r).
        #pragma unroll
        for (int nt = 0; nt < 4; ++nt) {
            #pragma unroll
            for (int r = 0; r < 4; ++r) {
                q2[(4 * lg + r) * STQ + nt * 16 + lr] = (bf16)acc[p][nt][r];
                k2[(4 * lg + r) * STQ + nt * 16 + lr] = (bf16)acc[p][4 + nt][r];
            }
            bf16x4 vv;
            vv[0] = (bf16)acc[p][8 + nt][0];
            vv[1] = (bf16)acc[p][8 + nt][1];
            vv[2] = (bf16)acc[p][8 + nt][2];
            vv[3] = (bf16)acc[p][8 + nt][3];
            *(bf16x4*)(vT + (nt * 16 + lr) * STV + lg * 4) = vv;  // transposed V
        }

        // QK^T on the stacked 16x16 two-batch block (K = 64 -> 2 MFMAs)
        f32x4 w4 = zero4;
        #pragma unroll
        for (int kh = 0; kh < 2; ++kh) {
            bf16x8 qa = *(const bf16x8*)(q2 + lr * STQ + kh * 32 + lg * 8);
            bf16x8 kb = *(const bf16x8*)(k2 + lr * STQ + kh * 32 + lg * 8);
            w4 = __builtin_amdgcn_mfma_f32_16x16x32_bf16(qa, kb, w4, 0, 0, 0);
        }

        // mask + softmax. lane holds col s' = lr, rows t' = 4*lg + r.
        const int sb = lr >> 3;    // key batch-half
        const int s  = lr & 7;     // key index within batch
        #pragma unroll
        for (int r = 0; r < 4; ++r) {
            int tp = 4 * lg + r;
            bool valid = ((tp >> 3) == sb) && (s <= (tp & 7));  // same batch & causal
            float val = valid ? w4[r] * qk_scale : -1e30f;
            float mx = val;
            mx = fmaxf(mx, __shfl_xor(mx, 1));
            mx = fmaxf(mx, __shfl_xor(mx, 2));
            mx = fmaxf(mx, __shfl_xor(mx, 4));
            float e = valid ? __expf(val - mx) : 0.f;
            float sm = e;
            sm += __shfl_xor(sm, 1);
            sm += __shfl_xor(sm, 2);
            sm += __shfl_xor(sm, 4);
            float pn = valid ? e / sm : 0.f;   // cross-batch quadrants -> exact 0
            wei[tp * STV + lr] = (bf16)pn;
        }

        // P @ V with K=32 (upper 16 k-slots are the pre-zeroed padding)
        bf16x8 pa = *(const bf16x8*)(wei + lr * STV + lg * 8);
        const int bb2 = wg * 4 + p * 2;
        #pragma unroll
        for (int nt = 0; nt < 4; ++nt) {
            bf16x8 vb = *(const bf16x8*)(vT + (nt * 16 + lr) * STV + lg * 8);
            f32x4 o = __builtin_amdgcn_mfma_f32_16x16x32_bf16(pa, vb, zero4, 0, 0, 0);
            #pragma unroll
            for (int r = 0; r < 4; ++r) {
                int tp = 4 * lg + r;
                __builtin_nontemporal_store(o[r],
                    &out[((size_t)(bb2 + (tp >> 3)) * TT + (tp & 7)) * HD + nt * 16 + lr]);
            }
        }
    }
}

// ---------------------------------------------------------------------------
extern "C" void kernel_launch(void* const* d_in, const int* in_sizes, int n_in,
                              void* d_out, int out_size, void* d_ws, size_t ws_size,
                              hipStream_t stream) {
    const float* x  = (const float*)d_in[0];
    const float* Wq = (const float*)d_in[1];
    const float* Wk = (const float*)d_in[2];
    const float* Wv = (const float*)d_in[3];
    float* out = (float*)d_out;

    const size_t wt_bytes = (size_t)12 * 12 * 64 * 8 * sizeof(bf16);  // 147456
    const int grid = NBATCH / 32;   // 1024 blocks, 8 waves x 4 batches each

    if (ws_size >= wt_bytes) {
        bf16* wt = (bf16*)d_ws;
        prep_wt<<<36, 256, 0, stream>>>(Wq, Wk, Wv, wt);
        fused_head<true><<<grid, 512, 0, stream>>>(x, wt, nullptr, nullptr, nullptr, out);
    } else {
        fused_head<false><<<grid, 512, 0, stream>>>(x, nullptr, Wq, Wk, Wv, out);
    }
}